// Round 1
// baseline (672.082 us; speedup 1.0000x reference)
//
#include <hip/hip_runtime.h>

// FixedSparseMultiHead: B=2, S=2048, D=1024, H=16, Hd=64, local band ±102.
// Round 0: correct all-fp32 baseline.
//   gemm_xwt<1> x3 : Q/K/V = x @ W^T + b  -> [B,H,S,Hd] in workspace
//   attn_local     : banded softmax attention (band width <= 236 per 32-row tile)
//   gemm_xwt<0>    : out = attn_out @ Wo^T + bo -> [B,S,D]
// Workspace: Q(16MB) K(16MB) V(16MB) AO(16MB) = 64MB.

#define SEQ   2048
#define DMODEL 1024
#define NHEAD 16
#define HDIM  64
#define HALFW 102      // w//2 for w = int(2048*0.1) = 204
#define BWMAX 240      // padded per-tile band width (max actual 236)

// ---------------------------------------------------------------------------
// GEMM: Y = X @ W^T + bias.  X:[4096,1024] row-major, W:[1024,1024] row-major
// (i.e. [N,K], K contiguous -> NT dot products, both operands K-contiguous).
// Tile: BM=128, BN=64, BK=16; 256 threads; per-thread 8x4 outputs.
// QKV=1: scatter-write Y into [B,H,S,Hd]. QKV=0: plain [M,N] row-major.
// ---------------------------------------------------------------------------
template<int QKV>
__global__ __launch_bounds__(256) void gemm_xwt(
    const float* __restrict__ X, const float* __restrict__ W,
    const float* __restrict__ bias, float* __restrict__ Y)
{
    __shared__ float As[16][132];   // [k][m], +4 pad
    __shared__ float Bs[16][68];    // [k][n], +4 pad

    const int tid = threadIdx.x;
    const int bx  = blockIdx.x;          // 512 blocks: 32 (m) x 16 (n)
    const int n0  = (bx & 15) * 64;
    const int m0  = (bx >> 4) * 128;
    const int ty  = tid >> 4;            // 0..15 -> 8 rows each
    const int tx  = tid & 15;            // 0..15 -> 4 cols each

    float acc[8][4];
#pragma unroll
    for (int r = 0; r < 8; ++r)
#pragma unroll
        for (int c = 0; c < 4; ++c) acc[r][c] = 0.f;

    const int lrow = tid >> 2;           // 0..63
    const int lkq  = (tid & 3) * 4;      // 0,4,8,12

    for (int k0 = 0; k0 < DMODEL; k0 += 16) {
        // global loads (regs)
        float4 a0 = *(const float4*)(X + (size_t)(m0 + lrow)      * DMODEL + k0 + lkq);
        float4 a1 = *(const float4*)(X + (size_t)(m0 + lrow + 64) * DMODEL + k0 + lkq);
        float4 b0 = *(const float4*)(W + (size_t)(n0 + lrow)      * DMODEL + k0 + lkq);

        __syncthreads();   // previous tile fully consumed
        As[lkq + 0][lrow] = a0.x; As[lkq + 1][lrow] = a0.y;
        As[lkq + 2][lrow] = a0.z; As[lkq + 3][lrow] = a0.w;
        As[lkq + 0][lrow + 64] = a1.x; As[lkq + 1][lrow + 64] = a1.y;
        As[lkq + 2][lrow + 64] = a1.z; As[lkq + 3][lrow + 64] = a1.w;
        Bs[lkq + 0][lrow] = b0.x; Bs[lkq + 1][lrow] = b0.y;
        Bs[lkq + 2][lrow] = b0.z; Bs[lkq + 3][lrow] = b0.w;
        __syncthreads();

#pragma unroll
        for (int k = 0; k < 16; ++k) {
            float4 av0 = *(const float4*)&As[k][ty * 8];
            float4 av1 = *(const float4*)&As[k][ty * 8 + 4];
            float4 bv  = *(const float4*)&Bs[k][tx * 4];
            float a[8] = {av0.x, av0.y, av0.z, av0.w, av1.x, av1.y, av1.z, av1.w};
            float b[4] = {bv.x, bv.y, bv.z, bv.w};
#pragma unroll
            for (int r = 0; r < 8; ++r)
#pragma unroll
                for (int c = 0; c < 4; ++c)
                    acc[r][c] += a[r] * b[c];
        }
    }

    const float4 bb = *(const float4*)(bias + n0 + tx * 4);

    if (QKV) {
        // Y layout [B,H,S,Hd]; tile spans one batch (m0 mult of 128) and one head (n0 mult of 64)
        const int b = m0 >> 11;
        const int h = n0 >> 6;
#pragma unroll
        for (int r = 0; r < 8; ++r) {
            const int m  = m0 + ty * 8 + r;
            const int ss = m & (SEQ - 1);
            float4 o;
            o.x = acc[r][0] + bb.x; o.y = acc[r][1] + bb.y;
            o.z = acc[r][2] + bb.z; o.w = acc[r][3] + bb.w;
            *(float4*)(Y + ((size_t)(b * NHEAD + h) * SEQ + ss) * HDIM + tx * 4) = o;
        }
    } else {
#pragma unroll
        for (int r = 0; r < 8; ++r) {
            const int m = m0 + ty * 8 + r;
            float4 o;
            o.x = acc[r][0] + bb.x; o.y = acc[r][1] + bb.y;
            o.z = acc[r][2] + bb.z; o.w = acc[r][3] + bb.w;
            *(float4*)(Y + (size_t)m * DMODEL + n0 + tx * 4) = o;
        }
    }
}

// ---------------------------------------------------------------------------
// Banded attention. One block = (b, h, 32-row q-tile). 256 threads = 4 waves.
// Phase 1: thread jj owns band column jj; computes scores for all 32 rows
//          (Q read via lane-uniform global loads -> scalar loads).
// Phase 1.5: wave w softmaxes rows 8w..8w+7 (shfl reductions over 64 lanes).
// Phase 2: wave w computes PV for its rows; lane owns d = lane.
// ---------------------------------------------------------------------------
__global__ __launch_bounds__(256) void attn_local(
    const float* __restrict__ Q, const float* __restrict__ K,
    const float* __restrict__ V, float* __restrict__ O)
{
    __shared__ float ssc[32][BWMAX];   // scores then probs, 30 KB

    const int tid = threadIdx.x;
    const int bx  = blockIdx.x;              // qt + 64*(h + 16*b)
    const int qt  = bx & 63;
    const int h   = (bx >> 6) & 15;
    const int b   = bx >> 10;
    const int i0  = qt * 32;

    const int jmin = max(0, i0 - HALFW);
    const int jmax = min(SEQ - 1, i0 + 31 + HALFW);
    const int BWt  = jmax - jmin + 1;        // <= 236

    const float* Qbh = Q + (size_t)(b * NHEAD + h) * SEQ * HDIM;
    const float* Kbh = K + (size_t)(b * NHEAD + h) * SEQ * HDIM;
    const float* Vbh = V + (size_t)(b * NHEAD + h) * SEQ * HDIM;

    // ---- phase 1: scores ----
    const int jj = tid;
    if (jj < BWt) {
        float acc[32];
#pragma unroll
        for (int i = 0; i < 32; ++i) acc[i] = 0.f;
        const float* kp = Kbh + (size_t)(jmin + jj) * HDIM;
        for (int d0 = 0; d0 < HDIM; d0 += 4) {
            const float4 kv = *(const float4*)(kp + d0);
#pragma unroll
            for (int i = 0; i < 32; ++i) {
                const float4 qv = *(const float4*)(Qbh + (size_t)(i0 + i) * HDIM + d0); // uniform -> s_load
                acc[i] += qv.x * kv.x + qv.y * kv.y + qv.z * kv.z + qv.w * kv.w;
            }
        }
#pragma unroll
        for (int i = 0; i < 32; ++i) ssc[i][jj] = acc[i] * 0.125f;   // /sqrt(64)
    }
    __syncthreads();

    // ---- phase 1.5: softmax (wave w owns rows 8w..8w+7) ----
    const int wv = tid >> 6, ln = tid & 63;
    float rs[8];
#pragma unroll
    for (int r = 0; r < 8; ++r) {
        const int i  = wv * 8 + r;
        const int qi = i0 + i;
        const int lo = max(0, qi - HALFW) - jmin;
        const int hi = min(SEQ - 1, qi + HALFW) - jmin;
        float m = -1e30f;
#pragma unroll
        for (int c = 0; c < 4; ++c) {
            const int j = ln + 64 * c;
            if (j >= lo && j <= hi) m = fmaxf(m, ssc[i][j]);
        }
#pragma unroll
        for (int off = 32; off > 0; off >>= 1) m = fmaxf(m, __shfl_xor(m, off));
        float sum = 0.f;
#pragma unroll
        for (int c = 0; c < 4; ++c) {
            const int j = ln + 64 * c;
            if (j < BWt) {
                float p = 0.f;
                if (j >= lo && j <= hi) p = __expf(ssc[i][j] - m);
                ssc[i][j] = p;
                sum += p;
            }
        }
#pragma unroll
        for (int off = 32; off > 0; off >>= 1) sum += __shfl_xor(sum, off);
        rs[r] = sum;
    }
    // no barrier: phase 2 reads only this wave's own rows (same-wave LDS ordering)

    // ---- phase 2: PV (lane owns d = ln) ----
    float oa[8];
#pragma unroll
    for (int r = 0; r < 8; ++r) oa[r] = 0.f;

    int jq = 0;
    for (; jq + 4 <= BWt; jq += 4) {
        const float v0 = Vbh[(size_t)(jmin + jq + 0) * HDIM + ln];
        const float v1 = Vbh[(size_t)(jmin + jq + 1) * HDIM + ln];
        const float v2 = Vbh[(size_t)(jmin + jq + 2) * HDIM + ln];
        const float v3 = Vbh[(size_t)(jmin + jq + 3) * HDIM + ln];
#pragma unroll
        for (int r = 0; r < 8; ++r) {
            const float4 p4 = *(const float4*)&ssc[wv * 8 + r][jq];   // uniform -> broadcast
            oa[r] += p4.x * v0 + p4.y * v1 + p4.z * v2 + p4.w * v3;
        }
    }
    for (; jq < BWt; ++jq) {
        const float v0 = Vbh[(size_t)(jmin + jq) * HDIM + ln];
#pragma unroll
        for (int r = 0; r < 8; ++r) oa[r] += ssc[wv * 8 + r][jq] * v0;
    }

#pragma unroll
    for (int r = 0; r < 8; ++r) {
        const int i = i0 + wv * 8 + r;
        O[((size_t)b * SEQ + i) * DMODEL + h * HDIM + ln] = oa[r] / rs[r];
    }
}

// ---------------------------------------------------------------------------
extern "C" void kernel_launch(void* const* d_in, const int* in_sizes, int n_in,
                              void* d_out, int out_size, void* d_ws, size_t ws_size,
                              hipStream_t stream) {
    const float* x  = (const float*)d_in[0];
    const float* Wq = (const float*)d_in[1];
    const float* bq = (const float*)d_in[2];
    const float* Wk = (const float*)d_in[3];
    const float* bk = (const float*)d_in[4];
    const float* Wv = (const float*)d_in[5];
    const float* bv = (const float*)d_in[6];
    const float* Wo = (const float*)d_in[7];
    const float* bo = (const float*)d_in[8];
    // d_in[9] = sparse_mask (bool local band) -- pattern is hard-coded (±102)

    float* out = (float*)d_out;
    float* ws  = (float*)d_ws;

    const size_t NELEM = (size_t)2 * SEQ * DMODEL;   // 4M floats = 16MB
    float* Qb = ws;
    float* Kb = ws + NELEM;
    float* Vb = ws + 2 * NELEM;
    float* AO = ws + 3 * NELEM;                       // total 64MB workspace

    gemm_xwt<1><<<512, 256, 0, stream>>>(x, Wq, bq, Qb);
    gemm_xwt<1><<<512, 256, 0, stream>>>(x, Wk, bk, Kb);
    gemm_xwt<1><<<512, 256, 0, stream>>>(x, Wv, bv, Vb);
    attn_local<<<2048, 256, 0, stream>>>(Qb, Kb, Vb, AO);
    gemm_xwt<0><<<512, 256, 0, stream>>>(AO, Wo, bo, out);
}

// Round 2
// 277.828 us; speedup vs baseline: 2.4191x; 2.4191x over previous
//
#include <hip/hip_runtime.h>

// FixedSparseMultiHead: B=2, S=2048, D=1024, H=16, Hd=64, local band ±102.
// Round 2: split-bf16 (bf16x3) MFMA GEMMs + XCD-swizzled banded attention.
//   split5     : x,Wq,Wk,Wv,Wo -> (hi,lo) bf16 pairs
//   gemm_qkv   : fused Q/K/V = x@W^T+b via 3-pass MFMA (Ahi*Bhi+Alo*Bhi+Ahi*Blo)
//   attn_local : banded softmax attention (fp32), writes AO as bf16 hi/lo pair
//   gemm_out   : out = AO@Wo^T+bo via 3-pass MFMA, fp32 out
// Fallback to round-1 all-fp32 path if ws_size < 80MB.

#define SEQ    2048
#define DMODEL 1024
#define NHEAD  16
#define HDIM   64
#define HALFW  102
#define BWMAX  240

typedef unsigned short u16;
typedef __attribute__((ext_vector_type(8))) short bf16x8;
typedef __attribute__((ext_vector_type(4))) float f32x4;

__device__ __forceinline__ u16 f2bf(float f) {
    unsigned u = __builtin_bit_cast(unsigned, f);
    unsigned r = (u + 0x7fffu + ((u >> 16) & 1u)) >> 16;   // RNE
    return (u16)r;
}
__device__ __forceinline__ float bf2f(u16 u) {
    return __builtin_bit_cast(float, ((unsigned)u) << 16);
}

__device__ __forceinline__ void gload16(const void* g, void* l) {
    __builtin_amdgcn_global_load_lds(
        (const __attribute__((address_space(1))) void*)g,
        (__attribute__((address_space(3))) void*)l, 16, 0, 0);
}

// ---------------------------------------------------------------------------
// split: fp32 -> (hi,lo) bf16.  y=0: x (4M elems); y=1..4: Wq/Wk/Wv/Wo (1M).
// ---------------------------------------------------------------------------
__global__ __launch_bounds__(256) void split5(
    const float* __restrict__ x,  const float* __restrict__ wq,
    const float* __restrict__ wk, const float* __restrict__ wv,
    const float* __restrict__ wo,
    u16* __restrict__ xhi, u16* __restrict__ xlo, u16* __restrict__ wbase)
{
    const int y = blockIdx.y;
    const float* src; u16* hi; u16* lo; int nblk;
    switch (y) {
      case 0:  src = x;  hi = xhi;             lo = xlo;             nblk = 4096; break;
      case 1:  src = wq; hi = wbase;           lo = wbase + 1048576; nblk = 1024; break;
      case 2:  src = wk; hi = wbase + 2097152; lo = wbase + 3145728; nblk = 1024; break;
      case 3:  src = wv; hi = wbase + 4194304; lo = wbase + 5242880; nblk = 1024; break;
      default: src = wo; hi = wbase + 6291456; lo = wbase + 7340032; nblk = 1024; break;
    }
    const int bx = blockIdx.x;
    if (bx >= nblk) return;
    const int i = (bx * 256 + threadIdx.x) * 4;
    const float4 v = *(const float4*)(src + i);
    ushort4 h, l;
    h.x = f2bf(v.x); l.x = f2bf(v.x - bf2f(h.x));
    h.y = f2bf(v.y); l.y = f2bf(v.y - bf2f(h.y));
    h.z = f2bf(v.z); l.z = f2bf(v.z - bf2f(h.z));
    h.w = f2bf(v.w); l.w = f2bf(v.w - bf2f(h.w));
    *(ushort4*)(hi + i) = h;
    *(ushort4*)(lo + i) = l;
}

// ---------------------------------------------------------------------------
// MFMA GEMM core: C[128x128] = sum over 3 passes of A*B^T, K=1024 per pass,
// BK=32, double-buffered LDS staged via global_load_lds width-16.
// A,B row-major [*,1024] bf16 (K contiguous). 256 thr = 4 waves (2x2 of 64x64).
// ---------------------------------------------------------------------------
__device__ __forceinline__ void gemm_core(
    const u16* __restrict__ Ahi, const u16* __restrict__ Alo,
    const u16* __restrict__ Bhi, const u16* __restrict__ Blo,
    int m0, int n0, u16* sA0, u16* sA1, u16* sB0, u16* sB1, f32x4 acc[4][4])
{
    const int tid = threadIdx.x, ln = tid & 63, wave = tid >> 6;
    const int wm = wave >> 1, wn = wave & 1;
    const int rl = ln & 15, kh = ln >> 4;          // frag row / k-half
    const int sr = ln >> 2, sc = (ln & 3) * 8;     // staging row / col (elems)

#pragma unroll
    for (int fm = 0; fm < 4; ++fm)
#pragma unroll
        for (int fn = 0; fn < 4; ++fn) acc[fm][fn] = (f32x4){0.f, 0.f, 0.f, 0.f};

    auto stage = [&](u16* dA, u16* dB, const u16* Ap, const u16* Bp, int k0) {
#pragma unroll
        for (int c = wave; c < 8; c += 4) {        // 2 chunks of 1KB per wave per operand
            gload16(Ap + (size_t)(m0 + c * 16 + sr) * 1024 + k0 + sc, dA + c * 512);
            gload16(Bp + (size_t)(n0 + c * 16 + sr) * 1024 + k0 + sc, dB + c * 512);
        }
    };

    stage(sA0, sB0, Ahi, Bhi, 0);
    __syncthreads();

    for (int t = 0; t < 96; ++t) {                 // 3 passes x 32 K-steps
        u16* As = (t & 1) ? sA1 : sA0;
        u16* Bs = (t & 1) ? sB1 : sB0;
        if (t + 1 < 96) {
            const int t1 = t + 1;
            const u16* Ap = (t1 >= 32 && t1 < 64) ? Alo : Ahi;
            const u16* Bp = (t1 >= 64) ? Blo : Bhi;
            stage((t & 1) ? sA0 : sA1, (t & 1) ? sB0 : sB1, Ap, Bp, (t1 & 31) << 5);
        }
        bf16x8 a[4], b[4];
#pragma unroll
        for (int fm = 0; fm < 4; ++fm)
            a[fm] = *(const bf16x8*)(As + (wm * 64 + fm * 16 + rl) * 32 + kh * 8);
#pragma unroll
        for (int fn = 0; fn < 4; ++fn)
            b[fn] = *(const bf16x8*)(Bs + (wn * 64 + fn * 16 + rl) * 32 + kh * 8);
#pragma unroll
        for (int fm = 0; fm < 4; ++fm)
#pragma unroll
            for (int fn = 0; fn < 4; ++fn)
                acc[fm][fn] = __builtin_amdgcn_mfma_f32_16x16x32_bf16(
                    a[fm], b[fn], acc[fm][fn], 0, 0, 0);
        __syncthreads();
    }
}

// Fused Q/K/V projection: blockIdx.y in {0,1,2} selects weights/bias/output.
__global__ __launch_bounds__(256) void gemm_qkv(
    const u16* __restrict__ xhi, const u16* __restrict__ xlo,
    const u16* __restrict__ wbase,
    const float* __restrict__ bq, const float* __restrict__ bk,
    const float* __restrict__ bvv,
    float* __restrict__ Qo, float* __restrict__ Ko, float* __restrict__ Vo)
{
    __shared__ u16 sA[2][4096], sB[2][4096];
    const int y = blockIdx.y;
    const u16* Bhi = wbase + (size_t)y * 2097152;
    const u16* Blo = Bhi + 1048576;
    const float* bias = (y == 0) ? bq : (y == 1) ? bk : bvv;
    float* Y = (y == 0) ? Qo : (y == 1) ? Ko : Vo;

    const int bx = blockIdx.x;                 // XCD swizzle: same m-tile -> same XCD
    const int mt = (bx & 7) * 4 + (bx >> 6);
    const int nt = (bx >> 3) & 7;
    const int m0 = mt * 128, n0 = nt * 128;

    f32x4 acc[4][4];
    gemm_core(xhi, xlo, Bhi, Blo, m0, n0, sA[0], sA[1], sB[0], sB[1], acc);

    const int tid = threadIdx.x, ln = tid & 63, wave = tid >> 6;
    const int wm = wave >> 1, wn = wave & 1;
    const int rl = ln & 15, kh = ln >> 4;
    const int b = m0 >> 11;
#pragma unroll
    for (int fn = 0; fn < 4; ++fn) {
        const int n = n0 + wn * 64 + fn * 16 + rl;
        const float bb = bias[n];
        const int h = n >> 6, hd = n & 63;
        float* yb = Y + (size_t)(b * NHEAD + h) * SEQ * HDIM + hd;
#pragma unroll
        for (int fm = 0; fm < 4; ++fm)
#pragma unroll
            for (int r = 0; r < 4; ++r) {
                const int m = m0 + wm * 64 + fm * 16 + kh * 4 + r;
                const int s = m & (SEQ - 1);
                yb[(size_t)s * HDIM] = acc[fm][fn][r] + bb;
            }
    }
}

// Final projection: out = AO@Wo^T + bo, plain [M,N] fp32 output.
__global__ __launch_bounds__(256) void gemm_out(
    const u16* __restrict__ Ahi, const u16* __restrict__ Alo,
    const u16* __restrict__ Bhi, const u16* __restrict__ Blo,
    const float* __restrict__ bias, float* __restrict__ Y)
{
    __shared__ u16 sA[2][4096], sB[2][4096];
    const int bx = blockIdx.x;
    const int mt = (bx & 7) * 4 + (bx >> 6);
    const int nt = (bx >> 3) & 7;
    const int m0 = mt * 128, n0 = nt * 128;

    f32x4 acc[4][4];
    gemm_core(Ahi, Alo, Bhi, Blo, m0, n0, sA[0], sA[1], sB[0], sB[1], acc);

    const int tid = threadIdx.x, ln = tid & 63, wave = tid >> 6;
    const int wm = wave >> 1, wn = wave & 1;
    const int rl = ln & 15, kh = ln >> 4;
#pragma unroll
    for (int fn = 0; fn < 4; ++fn) {
        const int n = n0 + wn * 64 + fn * 16 + rl;
        const float bb = bias[n];
#pragma unroll
        for (int fm = 0; fm < 4; ++fm)
#pragma unroll
            for (int r = 0; r < 4; ++r) {
                const int m = m0 + wm * 64 + fm * 16 + kh * 4 + r;
                Y[(size_t)m * DMODEL + n] = acc[fm][fn][r] + bb;
            }
    }
}

// ---------------------------------------------------------------------------
// Round-1 fp32 GEMM (fallback path only).
// ---------------------------------------------------------------------------
template<int QKV>
__global__ __launch_bounds__(256) void gemm_xwt(
    const float* __restrict__ X, const float* __restrict__ W,
    const float* __restrict__ bias, float* __restrict__ Y)
{
    __shared__ float As[16][132];
    __shared__ float Bs[16][68];
    const int tid = threadIdx.x;
    const int bx  = blockIdx.x;
    const int n0  = (bx & 15) * 64;
    const int m0  = (bx >> 4) * 128;
    const int ty  = tid >> 4, tx = tid & 15;
    float acc[8][4];
#pragma unroll
    for (int r = 0; r < 8; ++r)
#pragma unroll
        for (int c = 0; c < 4; ++c) acc[r][c] = 0.f;
    const int lrow = tid >> 2, lkq = (tid & 3) * 4;
    for (int k0 = 0; k0 < DMODEL; k0 += 16) {
        float4 a0 = *(const float4*)(X + (size_t)(m0 + lrow)      * DMODEL + k0 + lkq);
        float4 a1 = *(const float4*)(X + (size_t)(m0 + lrow + 64) * DMODEL + k0 + lkq);
        float4 b0 = *(const float4*)(W + (size_t)(n0 + lrow)      * DMODEL + k0 + lkq);
        __syncthreads();
        As[lkq + 0][lrow] = a0.x; As[lkq + 1][lrow] = a0.y;
        As[lkq + 2][lrow] = a0.z; As[lkq + 3][lrow] = a0.w;
        As[lkq + 0][lrow + 64] = a1.x; As[lkq + 1][lrow + 64] = a1.y;
        As[lkq + 2][lrow + 64] = a1.z; As[lkq + 3][lrow + 64] = a1.w;
        Bs[lkq + 0][lrow] = b0.x; Bs[lkq + 1][lrow] = b0.y;
        Bs[lkq + 2][lrow] = b0.z; Bs[lkq + 3][lrow] = b0.w;
        __syncthreads();
#pragma unroll
        for (int k = 0; k < 16; ++k) {
            float4 av0 = *(const float4*)&As[k][ty * 8];
            float4 av1 = *(const float4*)&As[k][ty * 8 + 4];
            float4 bv  = *(const float4*)&Bs[k][tx * 4];
            float a[8] = {av0.x, av0.y, av0.z, av0.w, av1.x, av1.y, av1.z, av1.w};
            float bb[4] = {bv.x, bv.y, bv.z, bv.w};
#pragma unroll
            for (int r = 0; r < 8; ++r)
#pragma unroll
                for (int c = 0; c < 4; ++c) acc[r][c] += a[r] * bb[c];
        }
    }
    const float4 bb = *(const float4*)(bias + n0 + tx * 4);
    if (QKV) {
        const int b = m0 >> 11, h = n0 >> 6;
#pragma unroll
        for (int r = 0; r < 8; ++r) {
            const int m = m0 + ty * 8 + r, ss = m & (SEQ - 1);
            float4 o = {acc[r][0] + bb.x, acc[r][1] + bb.y, acc[r][2] + bb.z, acc[r][3] + bb.w};
            *(float4*)(Y + ((size_t)(b * NHEAD + h) * SEQ + ss) * HDIM + tx * 4) = o;
        }
    } else {
#pragma unroll
        for (int r = 0; r < 8; ++r) {
            const int m = m0 + ty * 8 + r;
            float4 o = {acc[r][0] + bb.x, acc[r][1] + bb.y, acc[r][2] + bb.z, acc[r][3] + bb.w};
            *(float4*)(Y + (size_t)m * DMODEL + n0 + tx * 4) = o;
        }
    }
}

// ---------------------------------------------------------------------------
// Banded attention (fp32 math). SPLIT=1: write AO as bf16 hi/lo row-major
// [4096][1024]. XCD swizzle: each XCD owns 4 contiguous (b,h) strips.
// ---------------------------------------------------------------------------
template<int SPLIT>
__global__ __launch_bounds__(256) void attn_local(
    const float* __restrict__ Q, const float* __restrict__ K,
    const float* __restrict__ V, float* __restrict__ O,
    u16* __restrict__ Ohi, u16* __restrict__ Olo)
{
    __shared__ float ssc[32][BWMAX];

    const int tid = threadIdx.x;
    const int bx0 = blockIdx.x;
    const int bx  = (bx0 & 7) * 256 + (bx0 >> 3);   // XCD swizzle (2048 = 8*256)
    const int qt  = bx & 63;
    const int h   = (bx >> 6) & 15;
    const int b   = bx >> 10;
    const int i0  = qt * 32;

    const int jmin = max(0, i0 - HALFW);
    const int jmax = min(SEQ - 1, i0 + 31 + HALFW);
    const int BWt  = jmax - jmin + 1;

    const float* Qbh = Q + (size_t)(b * NHEAD + h) * SEQ * HDIM;
    const float* Kbh = K + (size_t)(b * NHEAD + h) * SEQ * HDIM;
    const float* Vbh = V + (size_t)(b * NHEAD + h) * SEQ * HDIM;

    const int jj = tid;
    if (jj < BWt) {
        float acc[32];
#pragma unroll
        for (int i = 0; i < 32; ++i) acc[i] = 0.f;
        const float* kp = Kbh + (size_t)(jmin + jj) * HDIM;
        for (int d0 = 0; d0 < HDIM; d0 += 4) {
            const float4 kv = *(const float4*)(kp + d0);
#pragma unroll
            for (int i = 0; i < 32; ++i) {
                const float4 qv = *(const float4*)(Qbh + (size_t)(i0 + i) * HDIM + d0);
                acc[i] += qv.x * kv.x + qv.y * kv.y + qv.z * kv.z + qv.w * kv.w;
            }
        }
#pragma unroll
        for (int i = 0; i < 32; ++i) ssc[i][jj] = acc[i] * 0.125f;
    }
    __syncthreads();

    const int wv = tid >> 6, ln = tid & 63;
    float rs[8];
#pragma unroll
    for (int r = 0; r < 8; ++r) {
        const int i  = wv * 8 + r;
        const int qi = i0 + i;
        const int lo = max(0, qi - HALFW) - jmin;
        const int hi = min(SEQ - 1, qi + HALFW) - jmin;
        float m = -1e30f;
#pragma unroll
        for (int c = 0; c < 4; ++c) {
            const int j = ln + 64 * c;
            if (j >= lo && j <= hi) m = fmaxf(m, ssc[i][j]);
        }
#pragma unroll
        for (int off = 32; off > 0; off >>= 1) m = fmaxf(m, __shfl_xor(m, off));
        float sum = 0.f;
#pragma unroll
        for (int c = 0; c < 4; ++c) {
            const int j = ln + 64 * c;
            if (j < BWt) {
                float p = 0.f;
                if (j >= lo && j <= hi) p = __expf(ssc[i][j] - m);
                ssc[i][j] = p;
                sum += p;
            }
        }
#pragma unroll
        for (int off = 32; off > 0; off >>= 1) sum += __shfl_xor(sum, off);
        rs[r] = sum;
    }

    float oa[8];
#pragma unroll
    for (int r = 0; r < 8; ++r) oa[r] = 0.f;
    int jq = 0;
    for (; jq + 4 <= BWt; jq += 4) {
        const float v0 = Vbh[(size_t)(jmin + jq + 0) * HDIM + ln];
        const float v1 = Vbh[(size_t)(jmin + jq + 1) * HDIM + ln];
        const float v2 = Vbh[(size_t)(jmin + jq + 2) * HDIM + ln];
        const float v3 = Vbh[(size_t)(jmin + jq + 3) * HDIM + ln];
#pragma unroll
        for (int r = 0; r < 8; ++r) {
            const float4 p4 = *(const float4*)&ssc[wv * 8 + r][jq];
            oa[r] += p4.x * v0 + p4.y * v1 + p4.z * v2 + p4.w * v3;
        }
    }
    for (; jq < BWt; ++jq) {
        const float v0 = Vbh[(size_t)(jmin + jq) * HDIM + ln];
#pragma unroll
        for (int r = 0; r < 8; ++r) oa[r] += ssc[wv * 8 + r][jq] * v0;
    }

#pragma unroll
    for (int r = 0; r < 8; ++r) {
        const int i = i0 + wv * 8 + r;
        const float o = oa[r] / rs[r];
        if (SPLIT) {
            const size_t idx = ((size_t)(b * SEQ + i)) * DMODEL + h * HDIM + ln;
            const u16 hh = f2bf(o);
            Ohi[idx] = hh;
            Olo[idx] = f2bf(o - bf2f(hh));
        } else {
            O[((size_t)b * SEQ + i) * DMODEL + h * HDIM + ln] = o;
        }
    }
}

// ---------------------------------------------------------------------------
extern "C" void kernel_launch(void* const* d_in, const int* in_sizes, int n_in,
                              void* d_out, int out_size, void* d_ws, size_t ws_size,
                              hipStream_t stream) {
    const float* x  = (const float*)d_in[0];
    const float* Wq = (const float*)d_in[1];
    const float* bq = (const float*)d_in[2];
    const float* Wk = (const float*)d_in[3];
    const float* bk = (const float*)d_in[4];
    const float* Wv = (const float*)d_in[5];
    const float* bv = (const float*)d_in[6];
    const float* Wo = (const float*)d_in[7];
    const float* bo = (const float*)d_in[8];

    float* out = (float*)d_out;
    float* ws  = (float*)d_ws;

    const size_t NELEM = (size_t)2 * SEQ * DMODEL;      // 4M elems
    float* Qb = ws;
    float* Kb = ws + NELEM;
    float* Vb = ws + 2 * NELEM;

    const size_t REQUIRED = (size_t)80 * 1024 * 1024;
    if (ws_size >= REQUIRED) {
        u16* xhi   = (u16*)(ws + 3 * NELEM);            // 48MB, 8MB
        u16* xlo   = xhi + NELEM;                        // 56MB, 8MB
        u16* aohi  = xhi;                                // reuse after QKV GEMMs
        u16* aolo  = xlo;
        u16* wbase = (u16*)((char*)d_ws + (size_t)64 * 1024 * 1024);  // 16MB of W pairs

        split5<<<dim3(4096, 5), 256, 0, stream>>>(x, Wq, Wk, Wv, Wo, xhi, xlo, wbase);
        gemm_qkv<<<dim3(256, 3), 256, 0, stream>>>(xhi, xlo, wbase, bq, bk, bv, Qb, Kb, Vb);
        attn_local<1><<<2048, 256, 0, stream>>>(Qb, Kb, Vb, nullptr, aohi, aolo);
        gemm_out<<<256, 256, 0, stream>>>(aohi, aolo, wbase + 6291456, wbase + 7340032, bo, out);
    } else {
        // fallback: round-1 all-fp32 path (needs 64MB)
        float* AO = ws + 3 * NELEM;
        gemm_xwt<1><<<512, 256, 0, stream>>>(x, Wq, bq, Qb);
        gemm_xwt<1><<<512, 256, 0, stream>>>(x, Wk, bk, Kb);
        gemm_xwt<1><<<512, 256, 0, stream>>>(x, Wv, bv, Vb);
        attn_local<0><<<2048, 256, 0, stream>>>(Qb, Kb, Vb, AO, nullptr, nullptr);
        gemm_xwt<0><<<512, 256, 0, stream>>>(AO, Wo, bo, out);
    }
}

// Round 4
// 222.988 us; speedup vs baseline: 3.0140x; 1.2459x over previous
//
#include <hip/hip_runtime.h>

// FixedSparseMultiHead: B=2, S=2048, D=1024, H=16, Hd=64, local band ±102.
// Round 4: fix PV straddle bug from round 3.
//   - jmin = max(0, q0-104): 8-elem (16B) aligned PV window, band still covered
//   - V^T rows padded to stride 2176, zeroed via hipMemsetAsync -> no PV clamp
//   split5 -> gemm_qkv (Q,K bf16 [B,H,S,64]; V^T bf16 [B,H,64,2176])
//          -> attn_mfma -> gemm_out.
// Fallback to all-fp32 path if ws_size < 80MB.

#define SEQ    2048
#define DMODEL 1024
#define NHEAD  16
#define HDIM   64
#define HALFW  102
#define BWMAX  240
#define VTS    2176    // padded V^T row stride (zeros beyond SEQ)

typedef unsigned short u16;
typedef __attribute__((ext_vector_type(8))) short bf16x8;
typedef __attribute__((ext_vector_type(4))) float f32x4;

__device__ __forceinline__ u16 f2bf(float f) {
    unsigned u = __builtin_bit_cast(unsigned, f);
    unsigned r = (u + 0x7fffu + ((u >> 16) & 1u)) >> 16;   // RNE
    return (u16)r;
}
__device__ __forceinline__ float bf2f(u16 u) {
    return __builtin_bit_cast(float, ((unsigned)u) << 16);
}

__device__ __forceinline__ void gload16(const void* g, void* l) {
    __builtin_amdgcn_global_load_lds(
        (const __attribute__((address_space(1))) void*)g,
        (__attribute__((address_space(3))) void*)l, 16, 0, 0);
}

// ---------------------------------------------------------------------------
// split: fp32 -> (hi,lo) bf16.  y=0: x (4M elems); y=1..4: Wq/Wk/Wv/Wo (1M).
// ---------------------------------------------------------------------------
__global__ __launch_bounds__(256) void split5(
    const float* __restrict__ x,  const float* __restrict__ wq,
    const float* __restrict__ wk, const float* __restrict__ wv,
    const float* __restrict__ wo,
    u16* __restrict__ xhi, u16* __restrict__ xlo, u16* __restrict__ wbase)
{
    const int y = blockIdx.y;
    const float* src; u16* hi; u16* lo; int nblk;
    switch (y) {
      case 0:  src = x;  hi = xhi;             lo = xlo;             nblk = 4096; break;
      case 1:  src = wq; hi = wbase;           lo = wbase + 1048576; nblk = 1024; break;
      case 2:  src = wk; hi = wbase + 2097152; lo = wbase + 3145728; nblk = 1024; break;
      case 3:  src = wv; hi = wbase + 4194304; lo = wbase + 5242880; nblk = 1024; break;
      default: src = wo; hi = wbase + 6291456; lo = wbase + 7340032; nblk = 1024; break;
    }
    const int bx = blockIdx.x;
    if (bx >= nblk) return;
    const int i = (bx * 256 + threadIdx.x) * 4;
    const float4 v = *(const float4*)(src + i);
    ushort4 h, l;
    h.x = f2bf(v.x); l.x = f2bf(v.x - bf2f(h.x));
    h.y = f2bf(v.y); l.y = f2bf(v.y - bf2f(h.y));
    h.z = f2bf(v.z); l.z = f2bf(v.z - bf2f(h.z));
    h.w = f2bf(v.w); l.w = f2bf(v.w - bf2f(h.w));
    *(ushort4*)(hi + i) = h;
    *(ushort4*)(lo + i) = l;
}

// ---------------------------------------------------------------------------
// MFMA GEMM core: C[128x128] += 3 passes (Ahi*Bhi, Alo*Bhi, Ahi*Blo), K=1024,
// BK=32, double-buffered LDS via global_load_lds width-16. 256 thr = 4 waves.
// ---------------------------------------------------------------------------
__device__ __forceinline__ void gemm_core(
    const u16* __restrict__ Ahi, const u16* __restrict__ Alo,
    const u16* __restrict__ Bhi, const u16* __restrict__ Blo,
    int m0, int n0, u16* sA0, u16* sA1, u16* sB0, u16* sB1, f32x4 acc[4][4])
{
    const int tid = threadIdx.x, ln = tid & 63, wave = tid >> 6;
    const int wm = wave >> 1, wn = wave & 1;
    const int rl = ln & 15, kh = ln >> 4;
    const int sr = ln >> 2, sc = (ln & 3) * 8;

#pragma unroll
    for (int fm = 0; fm < 4; ++fm)
#pragma unroll
        for (int fn = 0; fn < 4; ++fn) acc[fm][fn] = (f32x4){0.f, 0.f, 0.f, 0.f};

    auto stage = [&](u16* dA, u16* dB, const u16* Ap, const u16* Bp, int k0) {
#pragma unroll
        for (int c = wave; c < 8; c += 4) {
            gload16(Ap + (size_t)(m0 + c * 16 + sr) * 1024 + k0 + sc, dA + c * 512);
            gload16(Bp + (size_t)(n0 + c * 16 + sr) * 1024 + k0 + sc, dB + c * 512);
        }
    };

    stage(sA0, sB0, Ahi, Bhi, 0);
    __syncthreads();

    for (int t = 0; t < 96; ++t) {
        u16* As = (t & 1) ? sA1 : sA0;
        u16* Bs = (t & 1) ? sB1 : sB0;
        if (t + 1 < 96) {
            const int t1 = t + 1;
            const u16* Ap = (t1 >= 32 && t1 < 64) ? Alo : Ahi;
            const u16* Bp = (t1 >= 64) ? Blo : Bhi;
            stage((t & 1) ? sA0 : sA1, (t & 1) ? sB0 : sB1, Ap, Bp, (t1 & 31) << 5);
        }
        bf16x8 a[4], b[4];
#pragma unroll
        for (int fm = 0; fm < 4; ++fm)
            a[fm] = *(const bf16x8*)(As + (wm * 64 + fm * 16 + rl) * 32 + kh * 8);
#pragma unroll
        for (int fn = 0; fn < 4; ++fn)
            b[fn] = *(const bf16x8*)(Bs + (wn * 64 + fn * 16 + rl) * 32 + kh * 8);
#pragma unroll
        for (int fm = 0; fm < 4; ++fm)
#pragma unroll
            for (int fn = 0; fn < 4; ++fn)
                acc[fm][fn] = __builtin_amdgcn_mfma_f32_16x16x32_bf16(
                    a[fm], b[fn], acc[fm][fn], 0, 0, 0);
        __syncthreads();
    }
}

// ---------------------------------------------------------------------------
// Fused Q/K/V^T projection. y=0: Q bf16 [B,H,S,64]; y=1: K bf16 [B,H,S,64];
// y=2: V^T bf16 [B,H,64,VTS] via swapped operands (A=Wv, B=x).
// ---------------------------------------------------------------------------
__global__ __launch_bounds__(256) void gemm_qkv(
    const u16* __restrict__ xhi, const u16* __restrict__ xlo,
    const u16* __restrict__ wbase,
    const float* __restrict__ bq, const float* __restrict__ bk,
    const float* __restrict__ bvv,
    u16* __restrict__ Qo, u16* __restrict__ Ko, u16* __restrict__ VTo)
{
    __shared__ u16 sA[2][4096], sB[2][4096];
    const int y = blockIdx.y;
    const u16* Whi = wbase + (size_t)y * 2097152;
    const u16* Wlo = Whi + 1048576;

    const int bx = blockIdx.x;
    int m0, n0;
    if (y == 2) { m0 = (bx & 7) * 128; n0 = (bx >> 3) * 128; }          // m over D, n over 4096
    else { m0 = ((bx & 7) * 4 + (bx >> 6)) * 128; n0 = ((bx >> 3) & 7) * 128; }

    f32x4 acc[4][4];
    if (y == 2) gemm_core(Whi, Wlo, xhi, xlo, m0, n0, sA[0], sA[1], sB[0], sB[1], acc);
    else        gemm_core(xhi, xlo, Whi, Wlo, m0, n0, sA[0], sA[1], sB[0], sB[1], acc);

    const int tid = threadIdx.x, ln = tid & 63, wave = tid >> 6;
    const int wm = wave >> 1, wn = wave & 1;
    const int rl = ln & 15, kh = ln >> 4;

    if (y == 2) {
        // C[m=d-row][n=s-col] -> VT[(b*16+h)*64+hd][s], row stride VTS
#pragma unroll
        for (int fn = 0; fn < 4; ++fn) {
            const int n  = n0 + wn * 64 + fn * 16 + rl;   // 0..4095
            const int bb = n >> 11, s = n & (SEQ - 1);
#pragma unroll
            for (int fm = 0; fm < 4; ++fm)
#pragma unroll
                for (int r = 0; r < 4; ++r) {
                    const int m = m0 + wm * 64 + fm * 16 + kh * 4 + r;  // 0..1023
                    const float o = acc[fm][fn][r] + bvv[m];
                    const int row = (bb * NHEAD + (m >> 6)) * HDIM + (m & 63);
                    VTo[(size_t)row * VTS + s] = f2bf(o);
                }
        }
    } else {
        const float* bias = (y == 0) ? bq : bk;
        u16* Y = (y == 0) ? Qo : Ko;
        const int b = m0 >> 11;
#pragma unroll
        for (int fn = 0; fn < 4; ++fn) {
            const int n = n0 + wn * 64 + fn * 16 + rl;
            const float bb = bias[n];
            const int h = n >> 6, hd = n & 63;
#pragma unroll
            for (int fm = 0; fm < 4; ++fm)
#pragma unroll
                for (int r = 0; r < 4; ++r) {
                    const int m = m0 + wm * 64 + fm * 16 + kh * 4 + r;
                    const int s = m & (SEQ - 1);
                    Y[((size_t)(b * NHEAD + h) * SEQ + s) * HDIM + hd] =
                        f2bf(acc[fm][fn][r] + bb);
                }
        }
    }
}

// Final projection: out = AO@Wo^T + bo, fp32 out.
__global__ __launch_bounds__(256) void gemm_out(
    const u16* __restrict__ Ahi, const u16* __restrict__ Alo,
    const u16* __restrict__ Bhi, const u16* __restrict__ Blo,
    const float* __restrict__ bias, float* __restrict__ Y)
{
    __shared__ u16 sA[2][4096], sB[2][4096];
    const int bx = blockIdx.x;
    const int mt = (bx & 7) * 4 + (bx >> 6);
    const int nt = (bx >> 3) & 7;
    const int m0 = mt * 128, n0 = nt * 128;

    f32x4 acc[4][4];
    gemm_core(Ahi, Alo, Bhi, Blo, m0, n0, sA[0], sA[1], sB[0], sB[1], acc);

    const int tid = threadIdx.x, ln = tid & 63, wave = tid >> 6;
    const int wm = wave >> 1, wn = wave & 1;
    const int rl = ln & 15, kh = ln >> 4;
#pragma unroll
    for (int fn = 0; fn < 4; ++fn) {
        const int n = n0 + wn * 64 + fn * 16 + rl;
        const float bb = bias[n];
#pragma unroll
        for (int fm = 0; fm < 4; ++fm)
#pragma unroll
            for (int r = 0; r < 4; ++r) {
                const int m = m0 + wm * 64 + fm * 16 + kh * 4 + r;
                Y[(size_t)m * DMODEL + n] = acc[fm][fn][r] + bb;
            }
    }
}

// ---------------------------------------------------------------------------
// MFMA banded attention. 1024 blocks (XCD-swizzled), 4 independent waves;
// wave owns 16 q-rows. jmin = max(0, q0-104): 16B-aligned window, 14 tiles
// cover the band. QK^T: clamped K-row loads + exact masking. Softmax in regs.
// P -> bf16 via padded per-wave LDS. PV: V^T rows (stride VTS, zero-padded),
// unclamped aligned loads; masked P=0 kills out-of-range columns.
// ---------------------------------------------------------------------------
__global__ __launch_bounds__(256) void attn_mfma(
    const u16* __restrict__ Q, const u16* __restrict__ K,
    const u16* __restrict__ VT,
    u16* __restrict__ aohi, u16* __restrict__ aolo)
{
    __shared__ u16 P_lds[4][16][232];   // 232-elem stride: 2-way banks (free)

    const int tid = threadIdx.x, ln = tid & 63, wv = tid >> 6;
    const int bx0 = blockIdx.x;
    const int asg = (bx0 & 7) * 128 + (bx0 >> 3);   // 1024 = 8 XCD * 128
    const int bh  = asg >> 5;
    const int qt  = asg & 31;
    const int b   = bh >> 4, h = bh & 15;
    const int q0  = qt * 64 + wv * 16;
    const int jmin = (q0 >= 104) ? (q0 - 104) : 0;   // == 0 (mod 8)

    const u16* Qbh  = Q  + (size_t)bh * SEQ * HDIM;
    const u16* Kbh  = K  + (size_t)bh * SEQ * HDIM;
    const u16* VTbh = VT + (size_t)bh * HDIM * VTS;

    const int lr = ln & 15, lk = ln >> 4;

    // Q fragments (rows q0..q0+15, d 0..63)
    const bf16x8 qf0 = *(const bf16x8*)(Qbh + (size_t)(q0 + lr) * HDIM + lk * 8);
    const bf16x8 qf1 = *(const bf16x8*)(Qbh + (size_t)(q0 + lr) * HDIM + 32 + lk * 8);

    // ---- QK^T: 14 tiles x 2 MFMA ----
    f32x4 sc[14];
#pragma unroll
    for (int t = 0; t < 14; ++t) {
        const int j  = jmin + t * 16 + lr;
        const int jc = min(j, SEQ - 1);          // clamped load; masked below
        const u16* kp = Kbh + (size_t)jc * HDIM + lk * 8;
        const bf16x8 k0 = *(const bf16x8*)kp;
        const bf16x8 k1 = *(const bf16x8*)(kp + 32);
        f32x4 a = (f32x4){0.f, 0.f, 0.f, 0.f};
        a = __builtin_amdgcn_mfma_f32_16x16x32_bf16(qf0, k0, a, 0, 0, 0);
        a = __builtin_amdgcn_mfma_f32_16x16x32_bf16(qf1, k1, a, 0, 0, 0);
        sc[t] = a;
    }

    // ---- masked softmax, per C-row r (16-lane group shares a row) ----
    float lrow[4];
#pragma unroll
    for (int r = 0; r < 4; ++r) {
        const int i = q0 + lk * 4 + r;
        float mx = -3.0e38f;
#pragma unroll
        for (int t = 0; t < 14; ++t) {
            const int j = jmin + t * 16 + lr;
            float v = sc[t][r] * 0.125f;
            const bool ok = (j >= i - HALFW) && (j <= i + HALFW) && (j < SEQ);
            v = ok ? v : -3.0e38f;
            sc[t][r] = v;
            mx = fmaxf(mx, v);
        }
#pragma unroll
        for (int off = 8; off > 0; off >>= 1) mx = fmaxf(mx, __shfl_xor(mx, off));
        float sum = 0.f;
#pragma unroll
        for (int t = 0; t < 14; ++t) {
            const float p = __expf(sc[t][r] - mx);   // masked -> exactly 0
            sum += p;
            P_lds[wv][lk * 4 + r][t * 16 + lr] = f2bf(p);
        }
#pragma unroll
        for (int off = 8; off > 0; off >>= 1) sum += __shfl_xor(sum, off);
        lrow[r] = sum;
    }
    // same-wave LDS write->read; compiler inserts lgkmcnt waits

    // ---- PV: 7 k-chunks x 4 d-tiles, aligned unclamped V^T loads ----
    f32x4 ao[4];
#pragma unroll
    for (int nt = 0; nt < 4; ++nt) ao[nt] = (f32x4){0.f, 0.f, 0.f, 0.f};
#pragma unroll
    for (int kc = 0; kc < 7; ++kc) {
        const bf16x8 pf = *(const bf16x8*)&P_lds[wv][lr][kc * 32 + lk * 8];
        const int jb = jmin + kc * 32 + lk * 8;   // <= jmin+216+8 < VTS, 16B aligned
#pragma unroll
        for (int nt = 0; nt < 4; ++nt) {
            const bf16x8 vf = *(const bf16x8*)(VTbh + (size_t)(nt * 16 + lr) * VTS + jb);
            ao[nt] = __builtin_amdgcn_mfma_f32_16x16x32_bf16(pf, vf, ao[nt], 0, 0, 0);
        }
    }

    // ---- epilogue: AO -> hi/lo bf16 [4096][1024] ----
#pragma unroll
    for (int nt = 0; nt < 4; ++nt)
#pragma unroll
        for (int r = 0; r < 4; ++r) {
            const int i = q0 + lk * 4 + r;
            const float o = ao[nt][r] / lrow[r];
            const size_t idx = ((size_t)b * SEQ + i) * DMODEL + h * HDIM + nt * 16 + lr;
            const u16 hh = f2bf(o);
            aohi[idx] = hh;
            aolo[idx] = f2bf(o - bf2f(hh));
        }
}

// ---------------------------------------------------------------------------
// Round-1 fp32 path (fallback only).
// ---------------------------------------------------------------------------
template<int QKV>
__global__ __launch_bounds__(256) void gemm_xwt(
    const float* __restrict__ X, const float* __restrict__ W,
    const float* __restrict__ bias, float* __restrict__ Y)
{
    __shared__ float As[16][132];
    __shared__ float Bs[16][68];
    const int tid = threadIdx.x;
    const int bx  = blockIdx.x;
    const int n0  = (bx & 15) * 64;
    const int m0  = (bx >> 4) * 128;
    const int ty  = tid >> 4, tx = tid & 15;
    float acc[8][4];
#pragma unroll
    for (int r = 0; r < 8; ++r)
#pragma unroll
        for (int c = 0; c < 4; ++c) acc[r][c] = 0.f;
    const int lrow = tid >> 2, lkq = (tid & 3) * 4;
    for (int k0 = 0; k0 < DMODEL; k0 += 16) {
        float4 a0 = *(const float4*)(X + (size_t)(m0 + lrow)      * DMODEL + k0 + lkq);
        float4 a1 = *(const float4*)(X + (size_t)(m0 + lrow + 64) * DMODEL + k0 + lkq);
        float4 b0 = *(const float4*)(W + (size_t)(n0 + lrow)      * DMODEL + k0 + lkq);
        __syncthreads();
        As[lkq + 0][lrow] = a0.x; As[lkq + 1][lrow] = a0.y;
        As[lkq + 2][lrow] = a0.z; As[lkq + 3][lrow] = a0.w;
        As[lkq + 0][lrow + 64] = a1.x; As[lkq + 1][lrow + 64] = a1.y;
        As[lkq + 2][lrow + 64] = a1.z; As[lkq + 3][lrow + 64] = a1.w;
        Bs[lkq + 0][lrow] = b0.x; Bs[lkq + 1][lrow] = b0.y;
        Bs[lkq + 2][lrow] = b0.z; Bs[lkq + 3][lrow] = b0.w;
        __syncthreads();
#pragma unroll
        for (int k = 0; k < 16; ++k) {
            float4 av0 = *(const float4*)&As[k][ty * 8];
            float4 av1 = *(const float4*)&As[k][ty * 8 + 4];
            float4 bv  = *(const float4*)&Bs[k][tx * 4];
            float a[8] = {av0.x, av0.y, av0.z, av0.w, av1.x, av1.y, av1.z, av1.w};
            float bb[4] = {bv.x, bv.y, bv.z, bv.w};
#pragma unroll
            for (int r = 0; r < 8; ++r)
#pragma unroll
                for (int c = 0; c < 4; ++c) acc[r][c] += a[r] * bb[c];
        }
    }
    const float4 bb = *(const float4*)(bias + n0 + tx * 4);
    if (QKV) {
        const int b = m0 >> 11, h = n0 >> 6;
#pragma unroll
        for (int r = 0; r < 8; ++r) {
            const int m = m0 + ty * 8 + r, ss = m & (SEQ - 1);
            float4 o = {acc[r][0] + bb.x, acc[r][1] + bb.y, acc[r][2] + bb.z, acc[r][3] + bb.w};
            *(float4*)(Y + ((size_t)(b * NHEAD + h) * SEQ + ss) * HDIM + tx * 4) = o;
        }
    } else {
#pragma unroll
        for (int r = 0; r < 8; ++r) {
            const int m = m0 + ty * 8 + r;
            float4 o = {acc[r][0] + bb.x, acc[r][1] + bb.y, acc[r][2] + bb.z, acc[r][3] + bb.w};
            *(float4*)(Y + (size_t)m * DMODEL + n0 + tx * 4) = o;
        }
    }
}

__global__ __launch_bounds__(256) void attn_local_f32(
    const float* __restrict__ Q, const float* __restrict__ K,
    const float* __restrict__ V, float* __restrict__ O)
{
    __shared__ float ssc[32][BWMAX];
    const int tid = threadIdx.x;
    const int bx0 = blockIdx.x;
    const int bx  = (bx0 & 7) * 256 + (bx0 >> 3);
    const int qt  = bx & 63;
    const int h   = (bx >> 6) & 15;
    const int b   = bx >> 10;
    const int i0  = qt * 32;
    const int jmin = max(0, i0 - HALFW);
    const int jmax = min(SEQ - 1, i0 + 31 + HALFW);
    const int BWt  = jmax - jmin + 1;
    const float* Qbh = Q + (size_t)(b * NHEAD + h) * SEQ * HDIM;
    const float* Kbh = K + (size_t)(b * NHEAD + h) * SEQ * HDIM;
    const float* Vbh = V + (size_t)(b * NHEAD + h) * SEQ * HDIM;
    const int jj = tid;
    if (jj < BWt) {
        float acc[32];
#pragma unroll
        for (int i = 0; i < 32; ++i) acc[i] = 0.f;
        const float* kp = Kbh + (size_t)(jmin + jj) * HDIM;
        for (int d0 = 0; d0 < HDIM; d0 += 4) {
            const float4 kv = *(const float4*)(kp + d0);
#pragma unroll
            for (int i = 0; i < 32; ++i) {
                const float4 qv = *(const float4*)(Qbh + (size_t)(i0 + i) * HDIM + d0);
                acc[i] += qv.x * kv.x + qv.y * kv.y + qv.z * kv.z + qv.w * kv.w;
            }
        }
#pragma unroll
        for (int i = 0; i < 32; ++i) ssc[i][jj] = acc[i] * 0.125f;
    }
    __syncthreads();
    const int wv = tid >> 6, ln = tid & 63;
    float rs[8];
#pragma unroll
    for (int r = 0; r < 8; ++r) {
        const int i  = wv * 8 + r;
        const int qi = i0 + i;
        const int lo = max(0, qi - HALFW) - jmin;
        const int hi = min(SEQ - 1, qi + HALFW) - jmin;
        float m = -1e30f;
#pragma unroll
        for (int c = 0; c < 4; ++c) {
            const int j = ln + 64 * c;
            if (j >= lo && j <= hi) m = fmaxf(m, ssc[i][j]);
        }
#pragma unroll
        for (int off = 32; off > 0; off >>= 1) m = fmaxf(m, __shfl_xor(m, off));
        float sum = 0.f;
#pragma unroll
        for (int c = 0; c < 4; ++c) {
            const int j = ln + 64 * c;
            if (j < BWt) {
                float p = 0.f;
                if (j >= lo && j <= hi) p = __expf(ssc[i][j] - m);
                ssc[i][j] = p;
                sum += p;
            }
        }
#pragma unroll
        for (int off = 32; off > 0; off >>= 1) sum += __shfl_xor(sum, off);
        rs[r] = sum;
    }
    float oa[8];
#pragma unroll
    for (int r = 0; r < 8; ++r) oa[r] = 0.f;
    int jq = 0;
    for (; jq + 4 <= BWt; jq += 4) {
        const float v0 = Vbh[(size_t)(jmin + jq + 0) * HDIM + ln];
        const float v1 = Vbh[(size_t)(jmin + jq + 1) * HDIM + ln];
        const float v2 = Vbh[(size_t)(jmin + jq + 2) * HDIM + ln];
        const float v3 = Vbh[(size_t)(jmin + jq + 3) * HDIM + ln];
#pragma unroll
        for (int r = 0; r < 8; ++r) {
            const float4 p4 = *(const float4*)&ssc[wv * 8 + r][jq];
            oa[r] += p4.x * v0 + p4.y * v1 + p4.z * v2 + p4.w * v3;
        }
    }
    for (; jq < BWt; ++jq) {
        const float v0 = Vbh[(size_t)(jmin + jq) * HDIM + ln];
#pragma unroll
        for (int r = 0; r < 8; ++r) oa[r] += ssc[wv * 8 + r][jq] * v0;
    }
#pragma unroll
    for (int r = 0; r < 8; ++r) {
        const int i = i0 + wv * 8 + r;
        O[((size_t)b * SEQ + i) * DMODEL + h * HDIM + ln] = oa[r] / rs[r];
    }
}

// ---------------------------------------------------------------------------
extern "C" void kernel_launch(void* const* d_in, const int* in_sizes, int n_in,
                              void* d_out, int out_size, void* d_ws, size_t ws_size,
                              hipStream_t stream) {
    const float* x  = (const float*)d_in[0];
    const float* Wq = (const float*)d_in[1];
    const float* bq = (const float*)d_in[2];
    const float* Wk = (const float*)d_in[3];
    const float* bk = (const float*)d_in[4];
    const float* Wv = (const float*)d_in[5];
    const float* bv = (const float*)d_in[6];
    const float* Wo = (const float*)d_in[7];
    const float* bo = (const float*)d_in[8];

    float* out = (float*)d_out;

    const size_t REQUIRED = (size_t)80 * 1024 * 1024;
    if (ws_size >= REQUIRED) {
        const size_t M4 = 4194304;                       // 4M u16 = 8MB
        const size_t VT_ELEMS = (size_t)32 * HDIM * VTS; // 4,456,448 u16
        u16* Qb    = (u16*)d_ws;
        u16* Kb    = Qb + M4;
        u16* VTb   = Kb + M4;
        u16* aohi  = VTb + VT_ELEMS;
        u16* aolo  = aohi + M4;
        u16* xhi   = aolo + M4;
        u16* xlo   = xhi + M4;
        u16* wbase = xlo + M4;                           // 8M u16 = 16MB (total ~72.5MB)

        hipMemsetAsync(VTb, 0, VT_ELEMS * sizeof(u16), stream);  // zero pad cols
        split5<<<dim3(4096, 5), 256, 0, stream>>>(x, Wq, Wk, Wv, Wo, xhi, xlo, wbase);
        gemm_qkv<<<dim3(256, 3), 256, 0, stream>>>(xhi, xlo, wbase, bq, bk, bv, Qb, Kb, VTb);
        attn_mfma<<<1024, 256, 0, stream>>>(Qb, Kb, VTb, aohi, aolo);
        gemm_out<<<256, 256, 0, stream>>>(aohi, aolo, wbase + 6291456, wbase + 7340032, bo, out);
    } else {
        float* ws = (float*)d_ws;
        const size_t NELEM = (size_t)2 * SEQ * DMODEL;
        float* Qb = ws;
        float* Kb = ws + NELEM;
        float* Vb = ws + 2 * NELEM;
        float* AO = ws + 3 * NELEM;
        gemm_xwt<1><<<512, 256, 0, stream>>>(x, Wq, bq, Qb);
        gemm_xwt<1><<<512, 256, 0, stream>>>(x, Wk, bk, Kb);
        gemm_xwt<1><<<512, 256, 0, stream>>>(x, Wv, bv, Vb);
        attn_local_f32<<<2048, 256, 0, stream>>>(Qb, Kb, Vb, AO);
        gemm_xwt<0><<<512, 256, 0, stream>>>(AO, Wo, bo, out);
    }
}